// Round 5
// baseline (1029.443 us; speedup 1.0000x reference)
//
#include <hip/hip_runtime.h>

typedef unsigned int uint;
typedef unsigned short ushort;

typedef short short8 __attribute__((ext_vector_type(8)));
typedef float floatx4 __attribute__((ext_vector_type(4)));
typedef uint uintx4 __attribute__((ext_vector_type(4)));

#define FIN 512
#define HF  128
#define NC  40
#define KHOPS 10

__device__ __forceinline__ ushort f2bf(float f) {
    uint u = __float_as_uint(f);
    uint r = (u + 0x7fffu + ((u >> 16) & 1u)) >> 16;
    return (ushort)r;
}
__device__ __forceinline__ float bflo(uint v) { return __uint_as_float(v << 16); }
__device__ __forceinline__ float bfhi(uint v) { return __uint_as_float(v & 0xffff0000u); }
__device__ __forceinline__ uint packbf2(float a, float b) {
    return (uint)f2bf(a) | ((uint)f2bf(b) << 16);
}
__device__ __forceinline__ uint cvtpk(float lo, float hi) {
    uint r;
    asm("v_cvt_pk_bf16_f32 %0, %1, %2" : "=v"(r) : "v"(lo), "v"(hi));
    return r;
}
__device__ __forceinline__ float selu_f(float v) {
    const float l = 1.0507009873554805f, a = 1.6732632423543772f;
    return v > 0.f ? l * v : l * a * (expf(v) - 1.f);
}

// ---------------- W1 -> MFMA fragment layout (bf16) ----------------
__global__ void k_w1frag(const float* __restrict__ W1, ushort* __restrict__ w1f) {
    int id = blockIdx.x * 256 + threadIdx.x;
    if (id >= 16 * 8 * 64) return;
    int l = id & 63;
    int t = (id >> 6) & 7;
    int s = id >> 9;
    int row0 = s * 32 + (l >> 4) * 8;
    int col  = t * 16 + (l & 15);
    ushort* dst = w1f + (size_t)id * 8;
#pragma unroll
    for (int i = 0; i < 8; ++i)
        dst[i] = f2bf(W1[(row0 + i) * HF + col]);
}

// ---------------- W2 -> MFMA fragment layout (bf16, 48-col padded) ----------------
__global__ void k_w2frag(const float* __restrict__ W2, ushort* __restrict__ w2f) {
    int id = blockIdx.x * 256 + threadIdx.x;
    if (id >= 12 * 64) return;
    int l = id & 63;
    int tile = id >> 6;
    int kk = tile / 3, t = tile % 3;
    int row0 = kk * 32 + (l >> 4) * 8;
    int col  = t * 16 + (l & 15);
    ushort* dst = w2f + (size_t)id * 8;
#pragma unroll
    for (int i = 0; i < 8; ++i)
        dst[i] = (col < NC) ? f2bf(W2[(row0 + i) * NC + col]) : (ushort)0;
}

// ---------------- h = selu(x@W1+b1) -> hops[0] (bf16), fused fp0 ----------------
// Barrier-free: A-fragments loaded directly from global, B from L2-resident w1f.
__global__ __launch_bounds__(256) void k_gemm(
        const float* __restrict__ x, const ushort* __restrict__ w1f,
        const float* __restrict__ b1, ushort* __restrict__ h,
        const float* __restrict__ projw, const float* __restrict__ projb,
        float* __restrict__ fp0, int N) {
    int tid = threadIdx.x;
    int lane = tid & 63, w = tid >> 6;
    int rowblk = blockIdx.x * 128 + w * 32;      // wave owns 32 rows
    int kq = (lane >> 4) * 8;                    // k-chunk 0/8/16/24

    int r0 = rowblk + (lane & 15);
    int r1 = r0 + 16;
    size_t r0c = (size_t)min(r0, N - 1) * FIN;
    size_t r1c = (size_t)min(r1, N - 1) * FIN;

    floatx4 acc[2][8];
#pragma unroll
    for (int rt = 0; rt < 2; ++rt)
#pragma unroll
        for (int t = 0; t < 8; ++t) acc[rt][t] = (floatx4){0.f, 0.f, 0.f, 0.f};

    float4 aC[4];
    short8 bC[8];
    {
        const float* p0 = x + r0c + kq;
        const float* p1 = x + r1c + kq;
        aC[0] = *(const float4*)p0; aC[1] = *(const float4*)(p0 + 4);
        aC[2] = *(const float4*)p1; aC[3] = *(const float4*)(p1 + 4);
        const ushort* wp = w1f + ((size_t)lane) * 8;
#pragma unroll
        for (int t = 0; t < 8; ++t) bC[t] = *(const short8*)(wp + (size_t)t * 512);
    }

#pragma unroll 1
    for (int kk = 0; kk < 16; ++kk) {
        float4 aN[4];
        short8 bN[8];
        if (kk < 15) {
            int kb = (kk + 1) * 32 + kq;
            const float* p0 = x + r0c + kb;
            const float* p1 = x + r1c + kb;
            aN[0] = *(const float4*)p0; aN[1] = *(const float4*)(p0 + 4);
            aN[2] = *(const float4*)p1; aN[3] = *(const float4*)(p1 + 4);
            const ushort* wp = w1f + ((size_t)((kk + 1) * 8) * 64 + lane) * 8;
#pragma unroll
            for (int t = 0; t < 8; ++t) bN[t] = *(const short8*)(wp + (size_t)t * 512);
        }
        uintx4 pa0, pa1;
        pa0.x = cvtpk(aC[0].x, aC[0].y); pa0.y = cvtpk(aC[0].z, aC[0].w);
        pa0.z = cvtpk(aC[1].x, aC[1].y); pa0.w = cvtpk(aC[1].z, aC[1].w);
        pa1.x = cvtpk(aC[2].x, aC[2].y); pa1.y = cvtpk(aC[2].z, aC[2].w);
        pa1.z = cvtpk(aC[3].x, aC[3].y); pa1.w = cvtpk(aC[3].z, aC[3].w);
        short8 af0 = __builtin_bit_cast(short8, pa0);
        short8 af1 = __builtin_bit_cast(short8, pa1);
#pragma unroll
        for (int t = 0; t < 8; ++t) {
            acc[0][t] = __builtin_amdgcn_mfma_f32_16x16x32_bf16(af0, bC[t], acc[0][t], 0, 0, 0);
            acc[1][t] = __builtin_amdgcn_mfma_f32_16x16x32_bf16(af1, bC[t], acc[1][t], 0, 0, 0);
        }
        if (kk < 15) {
#pragma unroll
            for (int i = 0; i < 4; ++i) aC[i] = aN[i];
#pragma unroll
            for (int t = 0; t < 8; ++t) bC[t] = bN[t];
        }
    }

    // epilogue: selu + store bf16 + fused fp0 (dot with projw)
    int col0 = lane & 15;
    float fpd[2][4];
#pragma unroll
    for (int rt = 0; rt < 2; ++rt)
#pragma unroll
        for (int q = 0; q < 4; ++q) fpd[rt][q] = 0.f;
#pragma unroll
    for (int t = 0; t < 8; ++t) {
        int col = t * 16 + col0;
        float bias = b1[col];
        float pw = projw[col];
#pragma unroll
        for (int rt = 0; rt < 2; ++rt) {
#pragma unroll
            for (int q = 0; q < 4; ++q) {
                int row = rowblk + rt * 16 + (lane >> 4) * 4 + q;
                float v = selu_f(acc[rt][t][q] + bias);
                if (row < N) h[(size_t)row * HF + col] = f2bf(v);
                fpd[rt][q] = fmaf(v, pw, fpd[rt][q]);
            }
        }
    }
    // reduce fpd across the 16 lanes holding the same row
#pragma unroll
    for (int rt = 0; rt < 2; ++rt)
#pragma unroll
        for (int q = 0; q < 4; ++q) {
            float d = fpd[rt][q];
#pragma unroll
            for (int m = 1; m < 16; m <<= 1) d += __shfl_xor(d, m);
            fpd[rt][q] = d;
        }
    if (col0 == 0) {
        float pb = projb[0];
#pragma unroll
        for (int rt = 0; rt < 2; ++rt)
#pragma unroll
            for (int q = 0; q < 4; ++q) {
                int row = rowblk + rt * 16 + (lane >> 4) * 4 + q;
                if (row < N) fp0[row] = fpd[rt][q] + pb;
            }
    }
}

// ---------------- degree / dinv ----------------
__global__ void k_deg_init(int* __restrict__ deg, int N) {
    int i = blockIdx.x * 256 + threadIdx.x;
    if (i < N) deg[i] = 1;
}
__global__ void k_deg(const int* __restrict__ ei, int* __restrict__ deg, int E) {
    int e = blockIdx.x * 256 + threadIdx.x;
    if (e < E) atomicAdd(&deg[ei[E + e]], 1);
}
__global__ void k_dinv(const int* __restrict__ deg, float* __restrict__ dinv, int N) {
    int i = blockIdx.x * 256 + threadIdx.x;
    if (i < N) dinv[i] = rsqrtf((float)deg[i]);
}

// ---------------- exclusive scan of (deg-1) -> offsets ----------------
__global__ void k_scan1(const int* __restrict__ deg, int* __restrict__ offs,
                        int* __restrict__ bsum, int N) {
    __shared__ int lds[256];
    int tid = threadIdx.x;
    int base = blockIdx.x * 1024;
    int c[4], s = 0;
#pragma unroll
    for (int i = 0; i < 4; ++i) {
        int g = base + tid * 4 + i;
        c[i] = (g < N) ? (deg[g] - 1) : 0;
        s += c[i];
    }
    lds[tid] = s;
    __syncthreads();
    for (int off = 1; off < 256; off <<= 1) {
        int add = (tid >= off) ? lds[tid - off] : 0;
        __syncthreads();
        lds[tid] += add;
        __syncthreads();
    }
    int run = lds[tid] - s;
#pragma unroll
    for (int i = 0; i < 4; ++i) {
        int g = base + tid * 4 + i;
        if (g < N) offs[g] = run;
        run += c[i];
    }
    if (tid == 0) bsum[blockIdx.x] = lds[255];
}
__global__ void k_scan2(int* __restrict__ bsum, int nb) {
    if (blockIdx.x == 0 && threadIdx.x == 0) {
        int run = 0;
        for (int i = 0; i < nb; ++i) { int v = bsum[i]; bsum[i] = run; run += v; }
    }
}
__global__ void k_scan3(int* __restrict__ offs, const int* __restrict__ bsum, int N, int E) {
    int g = blockIdx.x * 256 + threadIdx.x;
    if (g < N) offs[g] += bsum[g >> 10];
    else if (g == N) offs[N] = E;
}

// ---------------- CSR fill: edat = {src, bits(dinv_r*dinv_c)} ----------------
__global__ void k_fill(const int* __restrict__ ei, const int* __restrict__ offs,
                       int* __restrict__ cursor, int2* __restrict__ edat,
                       const float* __restrict__ dinv, int E) {
    int e = blockIdx.x * 256 + threadIdx.x;
    if (e >= E) return;
    int r = ei[e], c = ei[E + e];
    int p = offs[c] + atomicAdd(&cursor[c], 1);
    edat[p] = make_int2(r, __float_as_int(dinv[r] * dinv[c]));
}

// ---------------- one hop: xn = A_hat @ xc, 16/32-deep gather batches ----
__global__ __launch_bounds__(256) void k_hop(
                      const ushort* __restrict__ xin, ushort* __restrict__ xout,
                      const int* __restrict__ offs, const int2* __restrict__ edat,
                      const float* __restrict__ dinv,
                      const float* __restrict__ projw, const float* __restrict__ projb,
                      float* __restrict__ fpk, int N) {
    int wid = (blockIdx.x * blockDim.x + threadIdx.x) >> 6;
    int lane = threadIdx.x & 63;
    if (wid >= N) return;
    const uint* xin2 = (const uint*)xin;
    float dn = dinv[wid];
    uint sv = xin2[(size_t)wid * 64 + lane];
    float wself = dn * dn;
    float acc0 = wself * bflo(sv);
    float acc1 = wself * bfhi(sv);
    int s = offs[wid], e = offs[wid + 1];
    for (int base = s; base < e; base += 64) {
        int idx = base + lane;
        int idxc = min(idx, e - 1);
        int2 ed = edat[idxc];
        int src = ed.x;
        float ew = (idx < e) ? __int_as_float(ed.y) : 0.f;
        int cnt = min(64, e - base);
        if (cnt <= 16) {
            uint xv[16];
            float wv[16];
#pragma unroll
            for (int u = 0; u < 16; ++u) {
                int sj = __builtin_amdgcn_readlane(src, u);
                wv[u] = __int_as_float(__builtin_amdgcn_readlane(__float_as_int(ew), u));
                xv[u] = xin2[(size_t)(uint)sj * 64 + lane];
            }
#pragma unroll
            for (int u = 0; u < 16; ++u) {
                acc0 = fmaf(wv[u], bflo(xv[u]), acc0);
                acc1 = fmaf(wv[u], bfhi(xv[u]), acc1);
            }
        } else {
            int groups = (cnt + 31) >> 5;
            for (int g = 0; g < groups; ++g) {
                int j = g * 32;
                uint xv[32];
                float wv[32];
#pragma unroll
                for (int u = 0; u < 32; ++u) {
                    int sj = __builtin_amdgcn_readlane(src, j + u);
                    wv[u] = __int_as_float(__builtin_amdgcn_readlane(__float_as_int(ew), j + u));
                    xv[u] = xin2[(size_t)(uint)sj * 64 + lane];
                }
#pragma unroll
                for (int u = 0; u < 32; ++u) {
                    acc0 = fmaf(wv[u], bflo(xv[u]), acc0);
                    acc1 = fmaf(wv[u], bfhi(xv[u]), acc1);
                }
            }
        }
    }
    ((uint*)xout)[(size_t)wid * 64 + lane] = packbf2(acc0, acc1);
    float dot = acc0 * projw[2 * lane] + acc1 * projw[2 * lane + 1];
#pragma unroll
    for (int m = 1; m < 64; m <<= 1) dot += __shfl_xor(dot, m);
    if (lane == 0) fpk[wid] = dot + projb[0];
}

// ---------------- mean of feature_pool over nodes ----------------
__global__ void k_msum(const float* __restrict__ fp, float* __restrict__ msum, int N) {
    int k = blockIdx.y;
    int i = blockIdx.x * 256 + threadIdx.x;
    int tid = threadIdx.x;
    float v = (i < N) ? fp[(size_t)k * N + i] : 0.f;
#pragma unroll
    for (int m = 1; m < 64; m <<= 1) v += __shfl_xor(v, m);
    __shared__ float ws4[4];
    if ((tid & 63) == 0) ws4[tid >> 6] = v;
    __syncthreads();
    if (tid == 0) atomicAdd(&msum[k], ws4[0] + ws4[1] + ws4[2] + ws4[3]);
}

// ---------------- share_w = l2norm(mean + hop_w) ----------------
__global__ void k_sharew(const float* __restrict__ msum, const float* __restrict__ hopw,
                         float* __restrict__ sharew, int N) {
    int k = threadIdx.x;
    float s = (k < KHOPS + 1) ? (msum[k] / (float)N + hopw[k]) : 0.f;
    float ss = s * s;
#pragma unroll
    for (int m = 1; m < 64; m <<= 1) ss += __shfl_xor(ss, m);
    float inv = 1.f / fmaxf(sqrtf(ss), 1e-12f);
    if (k < KHOPS + 1) sharew[k] = s * inv;
}

// ---------------- k_out: 16 nodes/block; single-pass combine (16B/thread),
//                  tanh -> LDS, MFMA K=128 N=48, log_softmax ----------------
__global__ __launch_bounds__(256) void k_out(
                     const ushort* __restrict__ hops, const float* __restrict__ fp,
                     const float* __restrict__ sharew, const ushort* __restrict__ w2f,
                     const float* __restrict__ b2, float* __restrict__ out, int N) {
    __shared__ __align__(16) char As[16 * 256];
    int tid = threadIdx.x;
    int nloc = tid >> 4;
    int fg = tid & 15;
    int node = blockIdx.x * 16 + nloc;
    bool valid = node < N;
    int nodec = valid ? node : N - 1;
    const uint* hops2 = (const uint*)hops;

    float c[KHOPS + 1];
    float ss = 0.f;
#pragma unroll
    for (int k = 0; k <= KHOPS; ++k) {
        float f = fp[(size_t)k * N + nodec];
        c[k] = f;
        ss += f * f;
    }
    float inv = 1.f / fmaxf(sqrtf(ss), 1e-12f);
#pragma unroll
    for (int k = 0; k <= KHOPS; ++k)
        c[k] = valid ? (0.2f * sharew[k] + 0.8f * c[k] * inv) : 0.f;

    const uint* base = hops2 + (size_t)nodec * 64 + fg * 4;
    size_t kstr = (size_t)N * 64;
    float a[8];
#pragma unroll
    for (int j = 0; j < 8; ++j) a[j] = 0.f;
#pragma unroll
    for (int k = 0; k <= KHOPS; ++k) {
        uint4 v = *(const uint4*)(base + (size_t)k * kstr);
        float ck = c[k];
        a[0] = fmaf(ck, bflo(v.x), a[0]);
        a[1] = fmaf(ck, bfhi(v.x), a[1]);
        a[2] = fmaf(ck, bflo(v.y), a[2]);
        a[3] = fmaf(ck, bfhi(v.y), a[3]);
        a[4] = fmaf(ck, bflo(v.z), a[4]);
        a[5] = fmaf(ck, bfhi(v.z), a[5]);
        a[6] = fmaf(ck, bflo(v.w), a[6]);
        a[7] = fmaf(ck, bfhi(v.w), a[7]);
    }
    uint4 pk;
    pk.x = packbf2(tanhf(a[0]), tanhf(a[1]));
    pk.y = packbf2(tanhf(a[2]), tanhf(a[3]));
    pk.z = packbf2(tanhf(a[4]), tanhf(a[5]));
    pk.w = packbf2(tanhf(a[6]), tanhf(a[7]));
    {
        int slotbyte = fg * 16;
        int addr = nloc * 256 + (slotbyte ^ ((nloc & 15) << 4));
        *(uint4*)(As + addr) = pk;
    }
    __syncthreads();

    int w = tid >> 6, lane = tid & 63;
    floatx4 acc = (floatx4){0.f, 0.f, 0.f, 0.f};
    if (w < 3) {
        int r = lane & 15;
#pragma unroll
        for (int kk = 0; kk < 4; ++kk) {
            int slotbyte = kk * 64 + (lane >> 4) * 16;
            int addr = r * 256 + (slotbyte ^ ((r & 15) << 4));
            short8 af = *(const short8*)(As + addr);
            const short8 bf = *(const short8*)(w2f + (size_t)((kk * 3 + w) * 64 + lane) * 8);
            acc = __builtin_amdgcn_mfma_f32_16x16x32_bf16(af, bf, acc, 0, 0, 0);
        }
    }
    __syncthreads();

    float* Ls = (float*)As;
    if (w < 3) {
        int cls = w * 16 + (lane & 15);
        float bb = (cls < NC) ? b2[cls] : 0.f;
#pragma unroll
        for (int q = 0; q < 4; ++q) {
            int row = (lane >> 4) * 4 + q;
            Ls[row * 48 + cls] = acc[q] + bb;
        }
    }
    __syncthreads();

    int r2 = tid >> 4;
    int c16 = tid & 15;
    float v0 = Ls[r2 * 48 + c16];
    float v1 = Ls[r2 * 48 + 16 + c16];
    bool has2 = c16 < 8;
    float v2 = has2 ? Ls[r2 * 48 + 32 + c16] : -INFINITY;
    float lm = fmaxf(fmaxf(v0, v1), v2);
#pragma unroll
    for (int m = 1; m < 16; m <<= 1) lm = fmaxf(lm, __shfl_xor(lm, m));
    float se = expf(v0 - lm) + expf(v1 - lm) + (has2 ? expf(v2 - lm) : 0.f);
#pragma unroll
    for (int m = 1; m < 16; m <<= 1) se += __shfl_xor(se, m);
    float lse = lm + logf(se);
    int nodeo = blockIdx.x * 16 + r2;
    if (nodeo < N) {
        out[(size_t)nodeo * NC + c16] = v0 - lse;
        out[(size_t)nodeo * NC + 16 + c16] = v1 - lse;
        if (has2) out[(size_t)nodeo * NC + 32 + c16] = v2 - lse;
    }
}

// ---------------- launch ----------------
extern "C" void kernel_launch(void* const* d_in, const int* in_sizes, int n_in,
                              void* d_out, int out_size, void* d_ws, size_t ws_size,
                              hipStream_t stream) {
    const float* x     = (const float*)d_in[0];
    const int*   ei    = (const int*)d_in[1];
    const float* W1    = (const float*)d_in[2];
    const float* b1    = (const float*)d_in[3];
    const float* projw = (const float*)d_in[4];
    const float* projb = (const float*)d_in[5];
    const float* hopw  = (const float*)d_in[6];
    const float* W2    = (const float*)d_in[7];
    const float* b2    = (const float*)d_in[8];
    float* out = (float*)d_out;

    int N = in_sizes[0] / FIN;
    int E = in_sizes[1] / 2;

    char* p = (char*)d_ws;
    auto alloc = [&](size_t bytes) -> char* {
        char* r = p;
        p += (bytes + 255) & ~(size_t)255;
        return r;
    };
    ushort* hops   = (ushort*)alloc((size_t)(KHOPS + 1) * N * HF * 2);
    int*    deg    = (int*)alloc((size_t)N * 4);
    float*  dinv   = (float*)alloc((size_t)N * 4);
    int*    offs   = (int*)alloc((size_t)(N + 1) * 4);
    int*    cursor = (int*)alloc((size_t)N * 4);
    int*    bsum   = (int*)alloc(4096);
    int2*   edat   = (int2*)alloc((size_t)E * 8);
    float*  fp     = (float*)alloc((size_t)(KHOPS + 1) * N * 4);
    float*  msum   = (float*)alloc(64);
    float*  sharew = (float*)alloc(64);
    ushort* w1f    = (ushort*)alloc((size_t)FIN * HF * 2);
    ushort* w2f    = (ushort*)alloc((size_t)12 * 64 * 8 * 2);

    int nb256N = (N + 255) / 256;
    int nbE    = (E + 255) / 256;
    int nbWave = (N + 3) / 4;
    int nb1024 = (N + 1023) / 1024;

    k_w1frag<<<32, 256, 0, stream>>>(W1, w1f);
    k_w2frag<<<3, 256, 0, stream>>>(W2, w2f);
    k_gemm<<<(N + 127) / 128, 256, 0, stream>>>(x, w1f, b1, hops, projw, projb, fp, N);

    k_deg_init<<<nb256N, 256, 0, stream>>>(deg, N);
    k_deg<<<nbE, 256, 0, stream>>>(ei, deg, E);
    k_dinv<<<nb256N, 256, 0, stream>>>(deg, dinv, N);

    k_scan1<<<nb1024, 256, 0, stream>>>(deg, offs, bsum, N);
    k_scan2<<<1, 64, 0, stream>>>(bsum, nb1024);
    k_scan3<<<(N + 256) / 256, 256, 0, stream>>>(offs, bsum, N, E);

    hipMemsetAsync(cursor, 0, (size_t)N * 4, stream);
    k_fill<<<nbE, 256, 0, stream>>>(ei, offs, cursor, edat, dinv, E);

    for (int k = 1; k <= KHOPS; ++k) {
        const ushort* xin = hops + (size_t)(k - 1) * N * HF;
        ushort* xout      = hops + (size_t)k * N * HF;
        k_hop<<<nbWave, 256, 0, stream>>>(xin, xout, offs, edat, dinv,
                                          projw, projb, fp + (size_t)k * N, N);
    }

    hipMemsetAsync(msum, 0, 64, stream);
    dim3 gm(nb256N, KHOPS + 1);
    k_msum<<<gm, 256, 0, stream>>>(fp, msum, N);
    k_sharew<<<1, 64, 0, stream>>>(msum, hopw, sharew, N);

    k_out<<<(N + 15) / 16, 256, 0, stream>>>(hops, fp, sharew, w2f, b2, out, N);
}

// Round 6
// 968.291 us; speedup vs baseline: 1.0632x; 1.0632x over previous
//
#include <hip/hip_runtime.h>

typedef unsigned int uint;
typedef unsigned short ushort;

typedef short short8 __attribute__((ext_vector_type(8)));
typedef float floatx4 __attribute__((ext_vector_type(4)));
typedef uint uintx4 __attribute__((ext_vector_type(4)));

#define FIN 512
#define HF  128
#define NC  40
#define KHOPS 10

__device__ __forceinline__ ushort f2bf(float f) {
    uint u = __float_as_uint(f);
    uint r = (u + 0x7fffu + ((u >> 16) & 1u)) >> 16;
    return (ushort)r;
}
__device__ __forceinline__ float bflo(uint v) { return __uint_as_float(v << 16); }
__device__ __forceinline__ float bfhi(uint v) { return __uint_as_float(v & 0xffff0000u); }
__device__ __forceinline__ uint packbf2(float a, float b) {
    return (uint)f2bf(a) | ((uint)f2bf(b) << 16);
}
__device__ __forceinline__ uint cvtpk(float lo, float hi) {
    uint r;
    asm("v_cvt_pk_bf16_f32 %0, %1, %2" : "=v"(r) : "v"(lo), "v"(hi));
    return r;
}
__device__ __forceinline__ float selu_f(float v) {
    const float l = 1.0507009873554805f, a = 1.6732632423543772f;
    return v > 0.f ? l * v : l * a * (expf(v) - 1.f);
}

#define GLDS16(g, l)                                                        \
    __builtin_amdgcn_global_load_lds(                                       \
        (const __attribute__((address_space(1))) void*)(g),                 \
        (__attribute__((address_space(3))) void*)(l), 16, 0, 0)

// ---------------- W1 -> MFMA fragment layout (bf16) ----------------
__global__ void k_w1frag(const float* __restrict__ W1, ushort* __restrict__ w1f) {
    int id = blockIdx.x * 256 + threadIdx.x;
    if (id >= 16 * 8 * 64) return;
    int l = id & 63;
    int t = (id >> 6) & 7;
    int s = id >> 9;
    int row0 = s * 32 + (l >> 4) * 8;
    int col  = t * 16 + (l & 15);
    ushort* dst = w1f + (size_t)id * 8;
#pragma unroll
    for (int i = 0; i < 8; ++i)
        dst[i] = f2bf(W1[(row0 + i) * HF + col]);
}

// ---------------- W2 -> MFMA fragment layout (bf16, 48-col padded) ----------------
__global__ void k_w2frag(const float* __restrict__ W2, ushort* __restrict__ w2f) {
    int id = blockIdx.x * 256 + threadIdx.x;
    if (id >= 12 * 64) return;
    int l = id & 63;
    int tile = id >> 6;
    int kk = tile / 3, t = tile % 3;
    int row0 = kk * 32 + (l >> 4) * 8;
    int col  = t * 16 + (l & 15);
    ushort* dst = w2f + (size_t)id * 8;
#pragma unroll
    for (int i = 0; i < 8; ++i)
        dst[i] = (col < NC) ? f2bf(W2[(row0 + i) * NC + col]) : (ushort)0;
}

// ---------------- h = selu(x@W1+b1) -> hops[0] (bf16), fused fp0 ----------------
// Per-wave private LDS double-buffer staged via global_load_lds (coalesced),
// both-sides XOR swizzle (inverse-swizzled global source, swizzled ds_read),
// counted vmcnt(12) pipeline, no __syncthreads.
__global__ __launch_bounds__(256) void k_gemm(
        const float* __restrict__ x, const ushort* __restrict__ w1f,
        const float* __restrict__ b1, ushort* __restrict__ h,
        const float* __restrict__ projw, const float* __restrict__ projb,
        float* __restrict__ fp0, int N) {
    __shared__ __align__(16) float bufA[4][32 * 32];
    __shared__ __align__(16) float bufB[4][32 * 32];
    int tid = threadIdx.x;
    int lane = tid & 63, w = tid >> 6;
    int rowblk = blockIdx.x * 128 + w * 32;   // wave owns 32 rows

    // staging geometry: each 1KB issue = 8 rows x 128 B; lane -> (row=lane>>3, slot=lane&7)
    int srl = lane >> 3;
    int ssl = lane & 7;
    int srcoff = ((ssl ^ srl) << 2);          // inverse-swizzled float offset within row
    float* bA = bufA[w];
    float* bB = bufB[w];

    floatx4 acc[2][8];
#pragma unroll
    for (int rt = 0; rt < 2; ++rt)
#pragma unroll
        for (int t = 0; t < 8; ++t) acc[rt][t] = (floatx4){0.f, 0.f, 0.f, 0.f};

    short8 bE[8], bO[8];

    auto STAGE = [&](float* lbuf, int kk) {
        int k0 = kk * 32;
#pragma unroll
        for (int i = 0; i < 4; ++i) {
            int row = rowblk + i * 8 + srl;
            const float* g = x + (size_t)min(row, N - 1) * FIN + k0 + srcoff;
            GLDS16(g, lbuf + i * 256);
        }
    };
    auto LOADB = [&](short8* bb, int kk) {
        const ushort* wp = w1f + ((size_t)(kk * 8) * 64 + lane) * 8;
#pragma unroll
        for (int t = 0; t < 8; ++t) bb[t] = *(const short8*)(wp + (size_t)t * 512);
    };

    int rl16 = lane & 15, cq = lane >> 4;
    int lo_sl = ((2 * cq) ^ (rl16 & 7)) << 4;
    int hi_sl = ((2 * cq + 1) ^ (rl16 & 7)) << 4;

    auto COMPUTE = [&](const float* lbuf, short8* bb) {
#pragma unroll
        for (int rt = 0; rt < 2; ++rt) {
            const char* rbase = (const char*)lbuf + (rt * 16 + rl16) * 128;
            float4 lo = *(const float4*)(rbase + lo_sl);
            float4 hi = *(const float4*)(rbase + hi_sl);
            uintx4 pa;
            pa.x = cvtpk(lo.x, lo.y); pa.y = cvtpk(lo.z, lo.w);
            pa.z = cvtpk(hi.x, hi.y); pa.w = cvtpk(hi.z, hi.w);
            short8 af = __builtin_bit_cast(short8, pa);
#pragma unroll
            for (int t = 0; t < 8; ++t)
                acc[rt][t] = __builtin_amdgcn_mfma_f32_16x16x32_bf16(af, bb[t], acc[rt][t], 0, 0, 0);
        }
    };

    STAGE(bA, 0);
    LOADB(bE, 0);
#pragma unroll 1
    for (int kk = 0; kk < 16; kk += 2) {
        // make sure prior reads of bB retired before overwrite, then prefetch odd step
        asm volatile("s_waitcnt lgkmcnt(0)" ::: "memory");
        __builtin_amdgcn_sched_barrier(0);
        STAGE(bB, kk + 1);
        LOADB(bO, kk + 1);
        asm volatile("s_waitcnt vmcnt(12)" ::: "memory");
        __builtin_amdgcn_sched_barrier(0);
        COMPUTE(bA, bE);
        asm volatile("s_waitcnt lgkmcnt(0)" ::: "memory");
        __builtin_amdgcn_sched_barrier(0);
        if (kk + 2 < 16) {
            STAGE(bA, kk + 2);
            LOADB(bE, kk + 2);
            asm volatile("s_waitcnt vmcnt(12)" ::: "memory");
        } else {
            asm volatile("s_waitcnt vmcnt(0)" ::: "memory");
        }
        __builtin_amdgcn_sched_barrier(0);
        COMPUTE(bB, bO);
    }

    // epilogue: selu + store bf16 + fused fp0 (dot with projw)
    int col0 = lane & 15;
    float fpd[2][4];
#pragma unroll
    for (int rt = 0; rt < 2; ++rt)
#pragma unroll
        for (int q = 0; q < 4; ++q) fpd[rt][q] = 0.f;
#pragma unroll
    for (int t = 0; t < 8; ++t) {
        int col = t * 16 + col0;
        float bias = b1[col];
        float pw = projw[col];
#pragma unroll
        for (int rt = 0; rt < 2; ++rt) {
#pragma unroll
            for (int q = 0; q < 4; ++q) {
                int row = rowblk + rt * 16 + (lane >> 4) * 4 + q;
                float v = selu_f(acc[rt][t][q] + bias);
                if (row < N) h[(size_t)row * HF + col] = f2bf(v);
                fpd[rt][q] = fmaf(v, pw, fpd[rt][q]);
            }
        }
    }
#pragma unroll
    for (int rt = 0; rt < 2; ++rt)
#pragma unroll
        for (int q = 0; q < 4; ++q) {
            float d = fpd[rt][q];
#pragma unroll
            for (int m = 1; m < 16; m <<= 1) d += __shfl_xor(d, m);
            fpd[rt][q] = d;
        }
    if (col0 == 0) {
        float pb = projb[0];
#pragma unroll
        for (int rt = 0; rt < 2; ++rt)
#pragma unroll
            for (int q = 0; q < 4; ++q) {
                int row = rowblk + rt * 16 + (lane >> 4) * 4 + q;
                if (row < N) fp0[row] = fpd[rt][q] + pb;
            }
    }
}

// ---------------- degree / dinv ----------------
__global__ void k_deg_init(int* __restrict__ deg, int N) {
    int i = blockIdx.x * 256 + threadIdx.x;
    if (i < N) deg[i] = 1;
}
__global__ void k_deg(const int* __restrict__ ei, int* __restrict__ deg, int E) {
    int e = blockIdx.x * 256 + threadIdx.x;
    if (e < E) atomicAdd(&deg[ei[E + e]], 1);
}
__global__ void k_dinv(const int* __restrict__ deg, float* __restrict__ dinv, int N) {
    int i = blockIdx.x * 256 + threadIdx.x;
    if (i < N) dinv[i] = rsqrtf((float)deg[i]);
}

// ---------------- exclusive scan of (deg-1) -> offsets ----------------
__global__ void k_scan1(const int* __restrict__ deg, int* __restrict__ offs,
                        int* __restrict__ bsum, int N) {
    __shared__ int lds[256];
    int tid = threadIdx.x;
    int base = blockIdx.x * 1024;
    int c[4], s = 0;
#pragma unroll
    for (int i = 0; i < 4; ++i) {
        int g = base + tid * 4 + i;
        c[i] = (g < N) ? (deg[g] - 1) : 0;
        s += c[i];
    }
    lds[tid] = s;
    __syncthreads();
    for (int off = 1; off < 256; off <<= 1) {
        int add = (tid >= off) ? lds[tid - off] : 0;
        __syncthreads();
        lds[tid] += add;
        __syncthreads();
    }
    int run = lds[tid] - s;
#pragma unroll
    for (int i = 0; i < 4; ++i) {
        int g = base + tid * 4 + i;
        if (g < N) offs[g] = run;
        run += c[i];
    }
    if (tid == 0) bsum[blockIdx.x] = lds[255];
}
__global__ void k_scan2(int* __restrict__ bsum, int nb) {
    if (blockIdx.x == 0 && threadIdx.x == 0) {
        int run = 0;
        for (int i = 0; i < nb; ++i) { int v = bsum[i]; bsum[i] = run; run += v; }
    }
}
__global__ void k_scan3(int* __restrict__ offs, const int* __restrict__ bsum, int N, int E) {
    int g = blockIdx.x * 256 + threadIdx.x;
    if (g < N) offs[g] += bsum[g >> 10];
    else if (g == N) offs[N] = E;
}

// ---------------- CSR fill: edat = {src, bits(dinv_r*dinv_c)} ----------------
__global__ void k_fill(const int* __restrict__ ei, const int* __restrict__ offs,
                       int* __restrict__ cursor, int2* __restrict__ edat,
                       const float* __restrict__ dinv, int E) {
    int e = blockIdx.x * 256 + threadIdx.x;
    if (e >= E) return;
    int r = ei[e], c = ei[E + e];
    int p = offs[c] + atomicAdd(&cursor[c], 1);
    edat[p] = make_int2(r, __float_as_int(dinv[r] * dinv[c]));
}

// ---------------- one hop: xn = A_hat @ xc, 16-deep gather groups ----
__global__ __launch_bounds__(256) void k_hop(
                      const ushort* __restrict__ xin, ushort* __restrict__ xout,
                      const int* __restrict__ offs, const int2* __restrict__ edat,
                      const float* __restrict__ dinv,
                      const float* __restrict__ projw, const float* __restrict__ projb,
                      float* __restrict__ fpk, int N) {
    int wid = (blockIdx.x * blockDim.x + threadIdx.x) >> 6;
    int lane = threadIdx.x & 63;
    if (wid >= N) return;
    const uint* xin2 = (const uint*)xin;
    float dn = dinv[wid];
    uint sv = xin2[(size_t)wid * 64 + lane];
    float wself = dn * dn;
    float acc0 = wself * bflo(sv);
    float acc1 = wself * bfhi(sv);
    int s = offs[wid], e = offs[wid + 1];
    for (int base = s; base < e; base += 64) {
        int idx = base + lane;
        int idxc = min(idx, e - 1);
        int2 ed = edat[idxc];
        int src = ed.x;
        float ew = (idx < e) ? __int_as_float(ed.y) : 0.f;
        int cnt = min(64, e - base);
        int groups = (cnt + 15) >> 4;
        for (int g = 0; g < groups; ++g) {
            int j = g * 16;
            uint xv[16];
            float wv[16];
#pragma unroll
            for (int u = 0; u < 16; ++u) {
                int sj = __builtin_amdgcn_readlane(src, j + u);
                wv[u] = __int_as_float(__builtin_amdgcn_readlane(__float_as_int(ew), j + u));
                xv[u] = xin2[(size_t)(uint)sj * 64 + lane];
            }
#pragma unroll
            for (int u = 0; u < 16; ++u) {
                acc0 = fmaf(wv[u], bflo(xv[u]), acc0);
                acc1 = fmaf(wv[u], bfhi(xv[u]), acc1);
            }
        }
    }
    ((uint*)xout)[(size_t)wid * 64 + lane] = packbf2(acc0, acc1);
    float dot = acc0 * projw[2 * lane] + acc1 * projw[2 * lane + 1];
#pragma unroll
    for (int m = 1; m < 64; m <<= 1) dot += __shfl_xor(dot, m);
    if (lane == 0) fpk[wid] = dot + projb[0];
}

// ---------------- mean of feature_pool over nodes ----------------
__global__ void k_msum(const float* __restrict__ fp, float* __restrict__ msum, int N) {
    int k = blockIdx.y;
    int i = blockIdx.x * 256 + threadIdx.x;
    int tid = threadIdx.x;
    float v = (i < N) ? fp[(size_t)k * N + i] : 0.f;
#pragma unroll
    for (int m = 1; m < 64; m <<= 1) v += __shfl_xor(v, m);
    __shared__ float ws4[4];
    if ((tid & 63) == 0) ws4[tid >> 6] = v;
    __syncthreads();
    if (tid == 0) atomicAdd(&msum[k], ws4[0] + ws4[1] + ws4[2] + ws4[3]);
}

// ---------------- share_w = l2norm(mean + hop_w) ----------------
__global__ void k_sharew(const float* __restrict__ msum, const float* __restrict__ hopw,
                         float* __restrict__ sharew, int N) {
    int k = threadIdx.x;
    float s = (k < KHOPS + 1) ? (msum[k] / (float)N + hopw[k]) : 0.f;
    float ss = s * s;
#pragma unroll
    for (int m = 1; m < 64; m <<= 1) ss += __shfl_xor(ss, m);
    float inv = 1.f / fmaxf(sqrtf(ss), 1e-12f);
    if (k < KHOPS + 1) sharew[k] = s * inv;
}

// ---------------- k_out: 16 nodes/block; single-pass combine (16B/thread),
//                  tanh -> LDS, MFMA K=128 N=48, log_softmax ----------------
__global__ __launch_bounds__(256) void k_out(
                     const ushort* __restrict__ hops, const float* __restrict__ fp,
                     const float* __restrict__ sharew, const ushort* __restrict__ w2f,
                     const float* __restrict__ b2, float* __restrict__ out, int N) {
    __shared__ __align__(16) char As[16 * 256];
    int tid = threadIdx.x;
    int nloc = tid >> 4;
    int fg = tid & 15;
    int node = blockIdx.x * 16 + nloc;
    bool valid = node < N;
    int nodec = valid ? node : N - 1;
    const uint* hops2 = (const uint*)hops;

    float c[KHOPS + 1];
    float ss = 0.f;
#pragma unroll
    for (int k = 0; k <= KHOPS; ++k) {
        float f = fp[(size_t)k * N + nodec];
        c[k] = f;
        ss += f * f;
    }
    float inv = 1.f / fmaxf(sqrtf(ss), 1e-12f);
#pragma unroll
    for (int k = 0; k <= KHOPS; ++k)
        c[k] = valid ? (0.2f * sharew[k] + 0.8f * c[k] * inv) : 0.f;

    const uint* base = hops2 + (size_t)nodec * 64 + fg * 4;
    size_t kstr = (size_t)N * 64;
    float a[8];
#pragma unroll
    for (int j = 0; j < 8; ++j) a[j] = 0.f;
#pragma unroll
    for (int k = 0; k <= KHOPS; ++k) {
        uint4 v = *(const uint4*)(base + (size_t)k * kstr);
        float ck = c[k];
        a[0] = fmaf(ck, bflo(v.x), a[0]);
        a[1] = fmaf(ck, bfhi(v.x), a[1]);
        a[2] = fmaf(ck, bflo(v.y), a[2]);
        a[3] = fmaf(ck, bfhi(v.y), a[3]);
        a[4] = fmaf(ck, bflo(v.z), a[4]);
        a[5] = fmaf(ck, bfhi(v.z), a[5]);
        a[6] = fmaf(ck, bflo(v.w), a[6]);
        a[7] = fmaf(ck, bfhi(v.w), a[7]);
    }
    uint4 pk;
    pk.x = packbf2(tanhf(a[0]), tanhf(a[1]));
    pk.y = packbf2(tanhf(a[2]), tanhf(a[3]));
    pk.z = packbf2(tanhf(a[4]), tanhf(a[5]));
    pk.w = packbf2(tanhf(a[6]), tanhf(a[7]));
    {
        int slotbyte = fg * 16;
        int addr = nloc * 256 + (slotbyte ^ ((nloc & 15) << 4));
        *(uint4*)(As + addr) = pk;
    }
    __syncthreads();

    int w = tid >> 6, lane = tid & 63;
    floatx4 acc = (floatx4){0.f, 0.f, 0.f, 0.f};
    if (w < 3) {
        int r = lane & 15;
#pragma unroll
        for (int kk = 0; kk < 4; ++kk) {
            int slotbyte = kk * 64 + (lane >> 4) * 16;
            int addr = r * 256 + (slotbyte ^ ((r & 15) << 4));
            short8 af = *(const short8*)(As + addr);
            const short8 bf = *(const short8*)(w2f + (size_t)((kk * 3 + w) * 64 + lane) * 8);
            acc = __builtin_amdgcn_mfma_f32_16x16x32_bf16(af, bf, acc, 0, 0, 0);
        }
    }
    __syncthreads();

    float* Ls = (float*)As;
    if (w < 3) {
        int cls = w * 16 + (lane & 15);
        float bb = (cls < NC) ? b2[cls] : 0.f;
#pragma unroll
        for (int q = 0; q < 4; ++q) {
            int row = (lane >> 4) * 4 + q;
            Ls[row * 48 + cls] = acc[q] + bb;
        }
    }
    __syncthreads();

    int r2 = tid >> 4;
    int c16 = tid & 15;
    float v0 = Ls[r2 * 48 + c16];
    float v1 = Ls[r2 * 48 + 16 + c16];
    bool has2 = c16 < 8;
    float v2 = has2 ? Ls[r2 * 48 + 32 + c16] : -INFINITY;
    float lm = fmaxf(fmaxf(v0, v1), v2);
#pragma unroll
    for (int m = 1; m < 16; m <<= 1) lm = fmaxf(lm, __shfl_xor(lm, m));
    float se = expf(v0 - lm) + expf(v1 - lm) + (has2 ? expf(v2 - lm) : 0.f);
#pragma unroll
    for (int m = 1; m < 16; m <<= 1) se += __shfl_xor(se, m);
    float lse = lm + logf(se);
    int nodeo = blockIdx.x * 16 + r2;
    if (nodeo < N) {
        out[(size_t)nodeo * NC + c16] = v0 - lse;
        out[(size_t)nodeo * NC + 16 + c16] = v1 - lse;
        if (has2) out[(size_t)nodeo * NC + 32 + c16] = v2 - lse;
    }
}

// ---------------- launch ----------------
extern "C" void kernel_launch(void* const* d_in, const int* in_sizes, int n_in,
                              void* d_out, int out_size, void* d_ws, size_t ws_size,
                              hipStream_t stream) {
    const float* x     = (const float*)d_in[0];
    const int*   ei    = (const int*)d_in[1];
    const float* W1    = (const float*)d_in[2];
    const float* b1    = (const float*)d_in[3];
    const float* projw = (const float*)d_in[4];
    const float* projb = (const float*)d_in[5];
    const float* hopw  = (const float*)d_in[6];
    const float* W2    = (const float*)d_in[7];
    const float* b2    = (const float*)d_in[8];
    float* out = (float*)d_out;

    int N = in_sizes[0] / FIN;
    int E = in_sizes[1] / 2;

    char* p = (char*)d_ws;
    auto alloc = [&](size_t bytes) -> char* {
        char* r = p;
        p += (bytes + 255) & ~(size_t)255;
        return r;
    };
    ushort* hops   = (ushort*)alloc((size_t)(KHOPS + 1) * N * HF * 2);
    int*    deg    = (int*)alloc((size_t)N * 4);
    float*  dinv   = (float*)alloc((size_t)N * 4);
    int*    offs   = (int*)alloc((size_t)(N + 1) * 4);
    int*    cursor = (int*)alloc((size_t)N * 4);
    int*    bsum   = (int*)alloc(4096);
    int2*   edat   = (int2*)alloc((size_t)E * 8);
    float*  fp     = (float*)alloc((size_t)(KHOPS + 1) * N * 4);
    float*  msum   = (float*)alloc(64);
    float*  sharew = (float*)alloc(64);
    ushort* w1f    = (ushort*)alloc((size_t)FIN * HF * 2);
    ushort* w2f    = (ushort*)alloc((size_t)12 * 64 * 8 * 2);

    int nb256N = (N + 255) / 256;
    int nbE    = (E + 255) / 256;
    int nbWave = (N + 3) / 4;
    int nb1024 = (N + 1023) / 1024;

    k_w1frag<<<32, 256, 0, stream>>>(W1, w1f);
    k_w2frag<<<3, 256, 0, stream>>>(W2, w2f);
    k_gemm<<<(N + 127) / 128, 256, 0, stream>>>(x, w1f, b1, hops, projw, projb, fp, N);

    k_deg_init<<<nb256N, 256, 0, stream>>>(deg, N);
    k_deg<<<nbE, 256, 0, stream>>>(ei, deg, E);
    k_dinv<<<nb256N, 256, 0, stream>>>(deg, dinv, N);

    k_scan1<<<nb1024, 256, 0, stream>>>(deg, offs, bsum, N);
    k_scan2<<<1, 64, 0, stream>>>(bsum, nb1024);
    k_scan3<<<(N + 256) / 256, 256, 0, stream>>>(offs, bsum, N, E);

    hipMemsetAsync(cursor, 0, (size_t)N * 4, stream);
    k_fill<<<nbE, 256, 0, stream>>>(ei, offs, cursor, edat, dinv, E);

    for (int k = 1; k <= KHOPS; ++k) {
        const ushort* xin = hops + (size_t)(k - 1) * N * HF;
        ushort* xout      = hops + (size_t)k * N * HF;
        k_hop<<<nbWave, 256, 0, stream>>>(xin, xout, offs, edat, dinv,
                                          projw, projb, fp + (size_t)k * N, N);
    }

    hipMemsetAsync(msum, 0, 64, stream);
    dim3 gm(nb256N, KHOPS + 1);
    k_msum<<<gm, 256, 0, stream>>>(fp, msum, N);
    k_sharew<<<1, 64, 0, stream>>>(msum, hopw, sharew, N);

    k_out<<<(N + 15) / 16, 256, 0, stream>>>(hops, fp, sharew, w2f, b2, out, N);
}